// Round 1
// baseline (1135.709 us; speedup 1.0000x reference)
//
#include <hip/hip_runtime.h>
#include <stdint.h>

// Problem constants (LlamaAttention: B=2, S=2048, HID=2048, H=16, KH=4, D=128)
#define Bc   2
#define Sc   2048
#define HIDc 2048
#define Hc   16
#define KHc  4
#define Dc   128
#define HDc  2048   // H*D
#define KHDc 512    // KH*D
#define SCALEc 0.08838834764831845f  // D^-0.5

typedef _Float16 f16;
typedef _Float16 f16x8 __attribute__((ext_vector_type(8)));
typedef float    f32x4 __attribute__((ext_vector_type(4)));

// ---------------------------------------------------------------- converts
__global__ __launch_bounds__(256) void conv_f32_f16(const float* __restrict__ in,
                                                    f16* __restrict__ out, int n) {
  int i = blockIdx.x * 256 + threadIdx.x;
  if (i < n) out[i] = (f16)in[i];
}

// ---------------------------------------------------------------- RoPE (in-place on f16 buffer)
// x layout: (B*S, heads*128). Each thread owns one (row, h, d<64) pair.
// cos/sin layout: (B*S, 128); cos[d] == cos[d+64] by construction.
__global__ __launch_bounds__(256) void rope_inplace(f16* __restrict__ x,
                                                    const float* __restrict__ cb,
                                                    const float* __restrict__ sb,
                                                    int log2h) {
  int idx = blockIdx.x * 256 + threadIdx.x;
  int d   = idx & 63;
  int h   = (idx >> 6) & ((1 << log2h) - 1);
  int row = idx >> (6 + log2h);
  size_t base = ((size_t)row << (7 + log2h)) + ((size_t)h << 7);
  float x1 = (float)x[base + d];
  float x2 = (float)x[base + 64 + d];
  float c  = cb[(size_t)row * 128 + d];
  float s  = sb[(size_t)row * 128 + d];
  x[base + d]      = (f16)(x1 * c - x2 * s);   // first half: q*cos - q_hi*sin
  x[base + 64 + d] = (f16)(x2 * c + x1 * s);   // second half: q_hi*cos + q_lo*sin
}

// ---------------------------------------------------------------- GEMM (f16 MFMA, 128x128 tile)
// C(M,N) = A(M,K) @ B(K,N). A,B f16 row-major. Out fp32 or f16 per flag.
// Block 256 thr = 4 waves (2x2), wave does 64x64 via 4x4 grid of 16x16x32 MFMAs.
// Layouts (verified m89/m92): A/B-frag [lane&15][quad*8+j]; C/D row=quad*4+r, col=lane&15.
__global__ __launch_bounds__(256) void gemm_f16(const f16* __restrict__ A,
                                                const f16* __restrict__ Bm,
                                                void* __restrict__ Cout,
                                                int M, int N, int K, int c_f16) {
  __shared__ f16 As[128][40];  // +8 pad: 80B stride -> <=2-way bank alias (free, m136)
  __shared__ f16 Bs[128][40];  // stored transposed: Bs[n][k]
  const int tid  = threadIdx.x;
  const int lane = tid & 63, wave = tid >> 6;
  const int quad = lane >> 4, l16 = lane & 15;
  const int wm = (wave >> 1) * 64, wn = (wave & 1) * 64;
  const int m0 = blockIdx.y * 128, n0 = blockIdx.x * 128;
  f32x4 acc[4][4] = {};
  const int ar = tid >> 2, ac = (tid & 3) * 8;   // A staging: 64 rows/pass x2
  const int br = tid >> 4, bc = (tid & 15) * 8;  // B staging: 16 k-rows/pass x2

  for (int k0 = 0; k0 < K; k0 += 32) {
    __syncthreads();  // protect LDS from previous iteration's readers
    *(uint4*)&As[ar][ac]      = *(const uint4*)&A[(size_t)(m0 + ar) * K + k0 + ac];
    *(uint4*)&As[ar + 64][ac] = *(const uint4*)&A[(size_t)(m0 + ar + 64) * K + k0 + ac];
    f16x8 b0 = *(const f16x8*)&Bm[(size_t)(k0 + br) * N + n0 + bc];
    f16x8 b1 = *(const f16x8*)&Bm[(size_t)(k0 + br + 16) * N + n0 + bc];
#pragma unroll
    for (int i = 0; i < 8; ++i) { Bs[bc + i][br] = b0[i]; Bs[bc + i][br + 16] = b1[i]; }
    __syncthreads();
    f16x8 af[4], bf[4];
#pragma unroll
    for (int i = 0; i < 4; ++i) af[i] = *(const f16x8*)&As[wm + i * 16 + l16][quad * 8];
#pragma unroll
    for (int j = 0; j < 4; ++j) bf[j] = *(const f16x8*)&Bs[wn + j * 16 + l16][quad * 8];
#pragma unroll
    for (int i = 0; i < 4; ++i)
#pragma unroll
      for (int j = 0; j < 4; ++j)
        acc[i][j] = __builtin_amdgcn_mfma_f32_16x16x32_f16(af[i], bf[j], acc[i][j], 0, 0, 0);
  }

  if (c_f16) {
    f16* C = (f16*)Cout;
#pragma unroll
    for (int i = 0; i < 4; ++i)
#pragma unroll
      for (int j = 0; j < 4; ++j)
#pragma unroll
        for (int r = 0; r < 4; ++r)
          C[(size_t)(m0 + wm + i * 16 + quad * 4 + r) * N + n0 + wn + j * 16 + l16] =
              (f16)acc[i][j][r];
  } else {
    float* C = (float*)Cout;
#pragma unroll
    for (int i = 0; i < 4; ++i)
#pragma unroll
      for (int j = 0; j < 4; ++j)
#pragma unroll
        for (int r = 0; r < 4; ++r)
          C[(size_t)(m0 + wm + i * 16 + quad * 4 + r) * N + n0 + wn + j * 16 + l16] =
              acc[i][j][r];
  }
}

// ---------------------------------------------------------------- fused causal attention
// Q: (B*S, H*D) f16 (roped). K,V: (B*S, KH*D) f16 (K roped). Out: (B*S, H*D) f16.
// Block = (q-tile of 64 rows, head h, batch b); 4 waves x 16 q-rows.
// K-tiles of 64, processed as 2 chunks of 32 cols (one MFMA K-depth for PV).
__global__ __launch_bounds__(256) void attn_fused(const f16* __restrict__ Q,
                                                  const f16* __restrict__ Kb,
                                                  const f16* __restrict__ Vb,
                                                  f16* __restrict__ Ob) {
  __shared__ f16 Ks[64][136];      // K rows; 272B stride -> 2-way alias
  __shared__ f16 Vt[128][72];      // V transposed: Vt[d][vrow]; 144B stride
  __shared__ f16 Ps[4][16][40];    // per-wave P transpose scratch (C-layout -> A-layout)
  const int tid  = threadIdx.x;
  const int lane = tid & 63, wave = tid >> 6;
  const int quad = lane >> 4, l16 = lane & 15;
  const int qt = blockIdx.x, h = blockIdx.y, b = blockIdx.z;
  const int kh = h >> 2;           // GQA: jnp.repeat => h // 4
  const int q0 = qt * 64;
  const int qbase = q0 + wave * 16;

  // Q fragments live in registers for the whole kernel (4 d-chunks of 32)
  f16x8 qf[4];
  {
    const f16* qp = Q + (size_t)(b * Sc + qbase + l16) * HDc + h * Dc + quad * 8;
#pragma unroll
    for (int c = 0; c < 4; ++c) qf[c] = *(const f16x8*)(qp + c * 32);
  }
  float m_i[4] = {-1e30f, -1e30f, -1e30f, -1e30f};
  float l_i[4] = {0.f, 0.f, 0.f, 0.f};
  f32x4 o[8] = {};

  const int ktiles = qt + 1;  // causal: k <= q
  for (int kt = 0; kt < ktiles; ++kt) {
    // stage K tile (64x128) and V tile transposed (128x64)
#pragma unroll
    for (int p = 0; p < 4; ++p) {
      int idx = p * 256 + tid;
      int r = idx >> 4, c8 = (idx & 15) * 8;
      size_t gbase = (size_t)(b * Sc + kt * 64 + r) * KHDc + kh * Dc + c8;
      *(uint4*)&Ks[r][c8] = *(const uint4*)(Kb + gbase);
      f16x8 v8 = *(const f16x8*)(Vb + gbase);
#pragma unroll
      for (int i = 0; i < 8; ++i) Vt[c8 + i][r] = v8[i];
    }
    __syncthreads();

#pragma unroll
    for (int kc = 0; kc < 2; ++kc) {   // two 32-col chunks
      f32x4 sa = {}, sb2 = {};
#pragma unroll
      for (int c = 0; c < 4; ++c) {    // d-chunks of 32
        f16x8 ka  = *(const f16x8*)&Ks[kc * 32 + l16][c * 32 + quad * 8];
        f16x8 kb2 = *(const f16x8*)&Ks[kc * 32 + 16 + l16][c * 32 + quad * 8];
        sa  = __builtin_amdgcn_mfma_f32_16x16x32_f16(qf[c], ka,  sa,  0, 0, 0);
        sb2 = __builtin_amdgcn_mfma_f32_16x16x32_f16(qf[c], kb2, sb2, 0, 0, 0);
      }
      const int ka_col = kt * 64 + kc * 32 + l16;
      const int kb_col = ka_col + 16;
      float pa[4], pb[4], alpha[4];
#pragma unroll
      for (int r = 0; r < 4; ++r) {
        int qrow = qbase + quad * 4 + r;
        float va = sa[r]  * SCALEc;
        float vb = sb2[r] * SCALEc;
        if (ka_col > qrow) va = -1e30f;  // causal mask (finite: NaN-safe)
        if (kb_col > qrow) vb = -1e30f;
        float mx = fmaxf(va, vb);
        mx = fmaxf(mx, __shfl_xor(mx, 1));
        mx = fmaxf(mx, __shfl_xor(mx, 2));
        mx = fmaxf(mx, __shfl_xor(mx, 4));
        mx = fmaxf(mx, __shfl_xor(mx, 8));
        float mnew = fmaxf(m_i[r], mx);
        float al = __expf(m_i[r] - mnew);
        va = __expf(va - mnew);
        vb = __expf(vb - mnew);
        float rs = va + vb;
        rs += __shfl_xor(rs, 1);
        rs += __shfl_xor(rs, 2);
        rs += __shfl_xor(rs, 4);
        rs += __shfl_xor(rs, 8);
        l_i[r] = l_i[r] * al + rs;
        m_i[r] = mnew;
        alpha[r] = al;
        pa[r] = va; pb[r] = vb;
      }
#pragma unroll
      for (int dt = 0; dt < 8; ++dt)
#pragma unroll
        for (int r = 0; r < 4; ++r) o[dt][r] *= alpha[r];
      // P: C-layout -> LDS -> A-layout (verified m120 pattern)
#pragma unroll
      for (int r = 0; r < 4; ++r) {
        Ps[wave][quad * 4 + r][l16]      = (f16)pa[r];
        Ps[wave][quad * 4 + r][16 + l16] = (f16)pb[r];
      }
      __syncthreads();
      f16x8 pf = *(const f16x8*)&Ps[wave][l16][quad * 8];
#pragma unroll
      for (int dt = 0; dt < 8; ++dt) {
        f16x8 vf = *(const f16x8*)&Vt[dt * 16 + l16][kc * 32 + quad * 8];
        o[dt] = __builtin_amdgcn_mfma_f32_16x16x32_f16(pf, vf, o[dt], 0, 0, 0);
      }
      __syncthreads();  // protect Ps/Ks/Vt before next chunk/tile overwrites
    }
  }

  float inv[4];
#pragma unroll
  for (int r = 0; r < 4; ++r) inv[r] = 1.0f / l_i[r];
#pragma unroll
  for (int dt = 0; dt < 8; ++dt)
#pragma unroll
    for (int r = 0; r < 4; ++r)
      Ob[(size_t)(b * Sc + qbase + quad * 4 + r) * HDc + h * Dc + dt * 16 + l16] =
          (f16)(o[dt][r] * inv[r]);
}

// ---------------------------------------------------------------- launch
extern "C" void kernel_launch(void* const* d_in, const int* in_sizes, int n_in,
                              void* d_out, int out_size, void* d_ws, size_t ws_size,
                              hipStream_t stream) {
  (void)in_sizes; (void)n_in; (void)out_size; (void)ws_size;
  const float* hs   = (const float*)d_in[0];
  const float* cosb = (const float*)d_in[1];
  const float* sinb = (const float*)d_in[2];
  // d_in[3] = attention_mask: pure causal, implemented in-kernel.
  const float* wq = (const float*)d_in[4];
  const float* wk = (const float*)d_in[5];
  const float* wv = (const float*)d_in[6];
  const float* wo = (const float*)d_in[7];
  float* out = (float*)d_out;

  char* ws = (char*)d_ws;
  size_t off = 0;
  auto alloc = [&](size_t elems) { f16* p = (f16*)(ws + off); off += elems * sizeof(f16); return p; };
  f16* hsF   = alloc((size_t)Bc * Sc * HIDc);        // 4096x2048
  f16* wqF   = alloc((size_t)HIDc * HDc);            // 2048x2048
  f16* wkF   = alloc((size_t)HIDc * KHDc);           // 2048x512
  f16* wvF   = alloc((size_t)HIDc * KHDc);
  f16* woF   = alloc((size_t)HDc * HIDc);
  f16* Qf    = alloc((size_t)Bc * Sc * HDc);         // roped in place
  f16* Kf    = alloc((size_t)Bc * Sc * KHDc);
  f16* Vf    = alloc((size_t)Bc * Sc * KHDc);
  f16* attnF = alloc((size_t)Bc * Sc * HDc);
  // total ~76 MB of d_ws

  conv_f32_f16<<<32768, 256, 0, stream>>>(hs, hsF, Bc * Sc * HIDc);
  conv_f32_f16<<<16384, 256, 0, stream>>>(wq, wqF, HIDc * HDc);
  conv_f32_f16<<<4096,  256, 0, stream>>>(wk, wkF, HIDc * KHDc);
  conv_f32_f16<<<4096,  256, 0, stream>>>(wv, wvF, HIDc * KHDc);
  conv_f32_f16<<<16384, 256, 0, stream>>>(wo, woF, HDc * HIDc);

  gemm_f16<<<dim3(16, 32), 256, 0, stream>>>(hsF, wqF, Qf, 4096, 2048, 2048, 1);
  gemm_f16<<<dim3(4,  32), 256, 0, stream>>>(hsF, wkF, Kf, 4096, 512,  2048, 1);
  gemm_f16<<<dim3(4,  32), 256, 0, stream>>>(hsF, wvF, Vf, 4096, 512,  2048, 1);

  rope_inplace<<<16384, 256, 0, stream>>>(Qf, cosb, sinb, 4);  // 16 heads
  rope_inplace<<<4096,  256, 0, stream>>>(Kf, cosb, sinb, 2);  // 4 kv heads

  attn_fused<<<dim3(Sc / 64, Hc, Bc), 256, 0, stream>>>(Qf, Kf, Vf, attnF);

  gemm_f16<<<dim3(16, 32), 256, 0, stream>>>(attnF, woF, out, 4096, 2048, 2048, 0);
}

// Round 2
// 508.515 us; speedup vs baseline: 2.2334x; 2.2334x over previous
//
#include <hip/hip_runtime.h>
#include <stdint.h>

// Problem constants (LlamaAttention: B=2, S=2048, HID=2048, H=16, KH=4, D=128)
#define Bc   2
#define Sc   2048
#define HIDc 2048
#define Hc   16
#define KHc  4
#define Dc   128
#define HDc  2048   // H*D
#define KHDc 512    // KH*D
#define QKVS 3072   // fused QKV row stride (2048 Q + 512 K + 512 V)
#define SCALEc 0.08838834764831845f  // D^-0.5
#define N_ITEMS 1024                 // 32 qtiles * 16 heads * 2 batch

typedef _Float16 f16;
typedef _Float16 f16x2 __attribute__((ext_vector_type(2)));
typedef _Float16 f16x4 __attribute__((ext_vector_type(4)));
typedef _Float16 f16x8 __attribute__((ext_vector_type(8)));
typedef float    f32x4 __attribute__((ext_vector_type(4)));

// async global->LDS DMA, 16B per lane; LDS dest = (wave-uniform) base + lane*16
__device__ __forceinline__ void gl_lds16(const void* g, void* l) {
  __builtin_amdgcn_global_load_lds(
      (const __attribute__((address_space(1))) unsigned int*)g,
      (__attribute__((address_space(3))) unsigned int*)l, 16, 0, 0);
}

// ---------------------------------------------------------------- counter init
__global__ void zero_ctr(int* c) { if (threadIdx.x == 0) *c = 0; }

// ---------------------------------------------------------------- convert (hs)
__global__ __launch_bounds__(256) void conv_f32_f16(const float* __restrict__ in,
                                                    f16* __restrict__ out, int n) {
  int i = blockIdx.x * 256 + threadIdx.x;
  if (i < n) out[i] = (f16)in[i];
}

// ---------------------------------------------------------------- weight transpose+convert
// in: f32 (2048 rows x C cols). out: f16 at rows [rowOff, rowOff+C), row stride 2048.
__global__ __launch_bounds__(256) void trw_f32_f16(const float* __restrict__ in,
                                                   f16* __restrict__ out,
                                                   int C, int rowOff) {
  __shared__ float Ld[64 * 65];  // 65: odd stride -> ~2-way banks both sides
  const int tid = threadIdx.x;
  const int r0 = blockIdx.y * 64, c0 = blockIdx.x * 64;
#pragma unroll
  for (int p = 0; p < 4; ++p) {
    int idx = p * 256 + tid;
    int r = idx >> 4, c4 = (idx & 15) * 4;
    float4 v = *(const float4*)&in[(size_t)(r0 + r) * C + c0 + c4];
    Ld[r * 65 + c4 + 0] = v.x; Ld[r * 65 + c4 + 1] = v.y;
    Ld[r * 65 + c4 + 2] = v.z; Ld[r * 65 + c4 + 3] = v.w;
  }
  __syncthreads();
#pragma unroll
  for (int p = 0; p < 4; ++p) {
    int idx = p * 256 + tid;
    int oc = idx >> 4, m4 = (idx & 15) * 4;
    f16x4 o;
#pragma unroll
    for (int i = 0; i < 4; ++i) o[i] = (f16)Ld[(m4 + i) * 65 + oc];
    *(f16x4*)&out[(size_t)(rowOff + c0 + oc) * 2048 + r0 + m4] = o;
  }
}

// ---------------------------------------------------------------- RoPE (strided, in place)
__global__ __launch_bounds__(256) void rope_s(f16* __restrict__ x,
                                              const float* __restrict__ cb,
                                              const float* __restrict__ sb,
                                              int colbase, int log2h) {
  int idx = blockIdx.x * 256 + threadIdx.x;
  int d   = idx & 63;
  int h   = (idx >> 6) & ((1 << log2h) - 1);
  int row = idx >> (6 + log2h);
  f16* p = x + (size_t)row * QKVS + colbase + h * 128;
  float x1 = (float)p[d], x2 = (float)p[64 + d];
  float c = cb[(size_t)row * 128 + d], s = sb[(size_t)row * 128 + d];
  p[d]      = (f16)(x1 * c - x2 * s);
  p[64 + d] = (f16)(x2 * c + x1 * s);
}

// ---------------------------------------------------------------- V transpose
// in: V cols of QKV (row stride 3072, colbase 2560). out: Vt[b][kh][d=128][s=2048]
__global__ __launch_bounds__(256) void v_tr(const f16* __restrict__ QKV,
                                            f16* __restrict__ Vt) {
  __shared__ f16 Ld[64 * 78];  // 78 f16 stride: ~2-way banks on both phases
  const int tid = threadIdx.x;
  const int s0 = blockIdx.x * 64, d0 = blockIdx.y * 64;
  const int b = blockIdx.z >> 2, kh = blockIdx.z & 3;
#pragma unroll
  for (int p = 0; p < 2; ++p) {
    int idx = p * 256 + tid;
    int sl = idx >> 3, dc8 = (idx & 7) * 8;
    f16x8 v = *(const f16x8*)&QKV[(size_t)(b * Sc + s0 + sl) * QKVS + 2560 + kh * 128 + d0 + dc8];
#pragma unroll
    for (int i = 0; i < 4; ++i) {
      f16x2 w; w[0] = v[2 * i]; w[1] = v[2 * i + 1];
      *(f16x2*)&Ld[sl * 78 + dc8 + 2 * i] = w;
    }
  }
  __syncthreads();
  {
    int dr = (tid >> 3) * 2, sc8 = (tid & 7) * 8;
    f16x8 r0v, r1v;
#pragma unroll
    for (int j = 0; j < 8; ++j) {
      f16x2 w = *(const f16x2*)&Ld[(sc8 + j) * 78 + dr];
      r0v[j] = w[0]; r1v[j] = w[1];
    }
    size_t obase = ((size_t)(b * KHc + kh) * 128 + d0 + dr) * Sc + s0 + sc8;
    *(f16x8*)&Vt[obase]      = r0v;
    *(f16x8*)&Vt[obase + Sc] = r1v;
  }
}

// ---------------------------------------------------------------- GEMM: C = A @ Bt^T
// A (M,K) f16 row-major; Bt (N,K) f16 row-major. 128x128 tile, BK=64,
// fragment-linear LDS + global_load_lds staging (m97 structure).
__global__ __launch_bounds__(256) void gemm_bt(const f16* __restrict__ A,
                                               const f16* __restrict__ Bt,
                                               void* __restrict__ Cout,
                                               int M, int N, int K, int c_f16) {
  __shared__ f16 Al[128 * 64];  // granule (g=m>>4, kq=k>>3, l16=m&15): slot=(g*8+kq)*16+l16
  __shared__ f16 Bl[128 * 64];
  const int tid  = threadIdx.x;
  const int lane = tid & 63, wave = tid >> 6;
  const int quad = lane >> 4, l16 = lane & 15;
  const int wm = (wave >> 1) * 64, wn = (wave & 1) * 64;
  const int m0 = blockIdx.y * 128, n0 = blockIdx.x * 128;
  f32x4 acc[4][4] = {};

  for (int k0 = 0; k0 < K; k0 += 64) {
    __syncthreads();
#pragma unroll
    for (int p = 0; p < 4; ++p) {
      const int g  = wave * 2 + (p >> 1);
      const int kq = (p & 1) * 4 + quad;
      gl_lds16(&A [(size_t)(m0 + g * 16 + l16) * K + k0 + kq * 8], &Al[(wave * 4 + p) * 64 * 8]);
      gl_lds16(&Bt[(size_t)(n0 + g * 16 + l16) * K + k0 + kq * 8], &Bl[(wave * 4 + p) * 64 * 8]);
    }
    __syncthreads();
#pragma unroll
    for (int ks = 0; ks < 2; ++ks) {
      f16x8 af[4], bf[4];
#pragma unroll
      for (int i = 0; i < 4; ++i)
        af[i] = *(const f16x8*)&Al[((((wave >> 1) * 4 + i) * 8 + ks * 4 + quad) * 16 + l16) * 8];
#pragma unroll
      for (int j = 0; j < 4; ++j)
        bf[j] = *(const f16x8*)&Bl[((((wave & 1) * 4 + j) * 8 + ks * 4 + quad) * 16 + l16) * 8];
#pragma unroll
      for (int i = 0; i < 4; ++i)
#pragma unroll
        for (int j = 0; j < 4; ++j)
          acc[i][j] = __builtin_amdgcn_mfma_f32_16x16x32_f16(af[i], bf[j], acc[i][j], 0, 0, 0);
    }
  }

  if (c_f16) {
    f16* C = (f16*)Cout;
#pragma unroll
    for (int i = 0; i < 4; ++i)
#pragma unroll
      for (int j = 0; j < 4; ++j)
#pragma unroll
        for (int r = 0; r < 4; ++r)
          C[(size_t)(m0 + wm + i * 16 + quad * 4 + r) * N + n0 + wn + j * 16 + l16] =
              (f16)acc[i][j][r];
  } else {
    float* C = (float*)Cout;
#pragma unroll
    for (int i = 0; i < 4; ++i)
#pragma unroll
      for (int j = 0; j < 4; ++j)
#pragma unroll
        for (int r = 0; r < 4; ++r)
          C[(size_t)(m0 + wm + i * 16 + quad * 4 + r) * N + n0 + wn + j * 16 + l16] =
              acc[i][j][r];
  }
}

// ---------------------------------------------------------------- fused causal attention v2
// Persistent blocks + atomic queue; fragment-linear LDS fed by global_load_lds;
// per-wave (barrier-free) P transpose. Items sorted by descending cost (qt).
__global__ __launch_bounds__(256) void attn_v2(const f16* __restrict__ QKV,
                                               const f16* __restrict__ Vt,
                                               f16* __restrict__ Ob,
                                               int* __restrict__ ctr) {
  __shared__ f16 Kl[64 * 128];   // granule ((kc*2+half)*4+c)*4+quad)*16+l16
  __shared__ f16 Vl[64 * 128];   // granule ((dt*2+kc)*4+quad)*16+l16
  __shared__ f16 Ps[4 * 512];    // per-wave 16x32 P tile: addr = w*512+(col>>3)*128+row*8+(col&7)
  __shared__ int item_s;
  const int tid  = threadIdx.x;
  const int lane = tid & 63, wave = tid >> 6;
  const int quad = lane >> 4, l16 = lane & 15;

  for (;;) {
    if (tid == 0) item_s = atomicAdd(ctr, 1);
    __syncthreads();
    const int item = item_s;
    if (item >= N_ITEMS) break;
    const int qt = 31 - (item >> 5);
    const int bh = item & 31;
    const int b = bh >> 4, h = bh & 15, kh = h >> 2;
    const int qbase = qt * 64 + wave * 16;

    f16x8 qf[4];
    {
      const f16* qp = QKV + (size_t)(b * Sc + qbase + l16) * QKVS + h * 128 + quad * 8;
#pragma unroll
      for (int c = 0; c < 4; ++c) qf[c] = *(const f16x8*)(qp + c * 32);
    }
    float m_i[4] = {-1e30f, -1e30f, -1e30f, -1e30f};
    float l_i[4] = {0.f, 0.f, 0.f, 0.f};
    f32x4 o[8] = {};

    const int ktiles = qt + 1;
    for (int kt = 0; kt < ktiles; ++kt) {
      __syncthreads();  // prior iteration's LDS reads done
#pragma unroll
      for (int p = 0; p < 4; ++p) {
        // K tile: rows wave*16+l16, d-cols p*32+quad*8
        gl_lds16(&QKV[(size_t)(b * Sc + kt * 64 + wave * 16 + l16) * QKVS + 2048 + kh * 128 + p * 32 + quad * 8],
                 &Kl[(wave * 4 + p) * 64 * 8]);
        // V tile (from Vt): d-rows dt*16+l16, k-cols kc*32+quad*8
        const int dt = wave * 2 + (p >> 1), kc = p & 1;
        gl_lds16(&Vt[(size_t)((b * KHc + kh) * 128 + dt * 16 + l16) * Sc + kt * 64 + kc * 32 + quad * 8],
                 &Vl[(wave * 4 + p) * 64 * 8]);
      }
      __syncthreads();  // barrier drains vmcnt -> DMA visible

#pragma unroll
      for (int kc = 0; kc < 2; ++kc) {
        f32x4 sa = {}, sb2 = {};
#pragma unroll
        for (int c = 0; c < 4; ++c) {
          f16x8 ka  = *(const f16x8*)&Kl[(((kc * 2 + 0) * 4 + c) * 4 + quad) * 16 * 8 + l16 * 8];
          f16x8 kb2 = *(const f16x8*)&Kl[(((kc * 2 + 1) * 4 + c) * 4 + quad) * 16 * 8 + l16 * 8];
          sa  = __builtin_amdgcn_mfma_f32_16x16x32_f16(qf[c], ka,  sa,  0, 0, 0);
          sb2 = __builtin_amdgcn_mfma_f32_16x16x32_f16(qf[c], kb2, sb2, 0, 0, 0);
        }
        const int ka_col = kt * 64 + kc * 32 + l16;
        const int kb_col = ka_col + 16;
        float pa[4], pb[4], alpha[4];
#pragma unroll
        for (int r = 0; r < 4; ++r) {
          int qrow = qbase + quad * 4 + r;
          float va = sa[r]  * SCALEc;
          float vb = sb2[r] * SCALEc;
          if (ka_col > qrow) va = -1e30f;
          if (kb_col > qrow) vb = -1e30f;
          float mx = fmaxf(va, vb);
          mx = fmaxf(mx, __shfl_xor(mx, 1));
          mx = fmaxf(mx, __shfl_xor(mx, 2));
          mx = fmaxf(mx, __shfl_xor(mx, 4));
          mx = fmaxf(mx, __shfl_xor(mx, 8));
          float mnew = fmaxf(m_i[r], mx);
          float al = __expf(m_i[r] - mnew);
          va = __expf(va - mnew);
          vb = __expf(vb - mnew);
          float rs = va + vb;
          rs += __shfl_xor(rs, 1);
          rs += __shfl_xor(rs, 2);
          rs += __shfl_xor(rs, 4);
          rs += __shfl_xor(rs, 8);
          l_i[r] = l_i[r] * al + rs;
          m_i[r] = mnew;
          alpha[r] = al;
          pa[r] = va; pb[r] = vb;
        }
#pragma unroll
        for (int dt = 0; dt < 8; ++dt)
#pragma unroll
          for (int r = 0; r < 4; ++r) o[dt][r] *= alpha[r];
        // P: C-layout -> A-layout, wave-local (no barrier). Read is lane-contiguous.
#pragma unroll
        for (int r = 0; r < 4; ++r) {
          Ps[wave * 512 + ((l16 >> 3) + 0) * 128 + (quad * 4 + r) * 8 + (l16 & 7)] = (f16)pa[r];
          Ps[wave * 512 + ((l16 >> 3) + 2) * 128 + (quad * 4 + r) * 8 + (l16 & 7)] = (f16)pb[r];
        }
        f16x8 pf = *(const f16x8*)&Ps[wave * 512 + quad * 128 + l16 * 8];
#pragma unroll
        for (int dt = 0; dt < 8; ++dt) {
          f16x8 vf = *(const f16x8*)&Vl[((dt * 2 + kc) * 4 + quad) * 16 * 8 + l16 * 8];
          o[dt] = __builtin_amdgcn_mfma_f32_16x16x32_f16(pf, vf, o[dt], 0, 0, 0);
        }
      }
    }

    float inv[4];
#pragma unroll
    for (int r = 0; r < 4; ++r) inv[r] = 1.0f / l_i[r];
#pragma unroll
    for (int dt = 0; dt < 8; ++dt)
#pragma unroll
      for (int r = 0; r < 4; ++r)
        Ob[(size_t)(b * Sc + qbase + quad * 4 + r) * HDc + h * 128 + dt * 16 + l16] =
            (f16)(o[dt][r] * inv[r]);
  }
}

// ---------------------------------------------------------------- launch
extern "C" void kernel_launch(void* const* d_in, const int* in_sizes, int n_in,
                              void* d_out, int out_size, void* d_ws, size_t ws_size,
                              hipStream_t stream) {
  (void)in_sizes; (void)n_in; (void)out_size; (void)ws_size;
  const float* hs   = (const float*)d_in[0];
  const float* cosb = (const float*)d_in[1];
  const float* sinb = (const float*)d_in[2];
  // d_in[3] = attention_mask: pure causal, in-kernel.
  const float* wq = (const float*)d_in[4];
  const float* wk = (const float*)d_in[5];
  const float* wv = (const float*)d_in[6];
  const float* wo = (const float*)d_in[7];
  float* out = (float*)d_out;

  char* ws = (char*)d_ws;
  int*  ctr = (int*)ws;
  size_t off = 256;
  auto alloc = [&](size_t elems) { f16* p = (f16*)(ws + off); off += elems * sizeof(f16); return p; };
  f16* hsF    = alloc((size_t)Bc * Sc * HIDc);     // 16.8 MB (reused as attn output)
  f16* wqkvT  = alloc((size_t)QKVS * HIDc);        // 12.6 MB
  f16* woT    = alloc((size_t)HIDc * HDc);         //  8.4 MB
  f16* QKVf   = alloc((size_t)Bc * Sc * QKVS);     // 25.2 MB
  f16* Vt_g   = alloc((size_t)Bc * KHc * Dc * Sc); //  4.2 MB
  f16* attnF  = hsF;                               // hsF dead after QKV GEMM

  zero_ctr<<<1, 64, 0, stream>>>(ctr);
  conv_f32_f16<<<32768, 256, 0, stream>>>(hs, hsF, Bc * Sc * HIDc);
  trw_f32_f16<<<dim3(32, 32), 256, 0, stream>>>(wq, wqkvT, 2048, 0);
  trw_f32_f16<<<dim3(8,  32), 256, 0, stream>>>(wk, wqkvT, 512, 2048);
  trw_f32_f16<<<dim3(8,  32), 256, 0, stream>>>(wv, wqkvT, 512, 2560);
  trw_f32_f16<<<dim3(32, 32), 256, 0, stream>>>(wo, woT, 2048, 0);

  gemm_bt<<<dim3(24, 32), 256, 0, stream>>>(hsF, wqkvT, QKVf, 4096, QKVS, 2048, 1);

  rope_s<<<16384, 256, 0, stream>>>(QKVf, cosb, sinb, 0, 4);     // Q: 16 heads
  rope_s<<<4096,  256, 0, stream>>>(QKVf, cosb, sinb, 2048, 2);  // K: 4 kv heads
  v_tr<<<dim3(32, 2, 8), 256, 0, stream>>>(QKVf, Vt_g);

  attn_v2<<<512, 256, 0, stream>>>(QKVf, Vt_g, attnF, ctr);

  gemm_bt<<<dim3(16, 32), 256, 0, stream>>>(attnF, woT, out, 4096, 2048, 2048, 0);
}

// Round 3
// 466.754 us; speedup vs baseline: 2.4332x; 1.0895x over previous
//
#include <hip/hip_runtime.h>
#include <stdint.h>

// Problem constants (LlamaAttention: B=2, S=2048, HID=2048, H=16, KH=4, D=128)
#define Bc   2
#define Sc   2048
#define HIDc 2048
#define Hc   16
#define KHc  4
#define Dc   128
#define HDc  2048   // H*D
#define KHDc 512    // KH*D
#define QKVS 3072   // fused QKV row stride (2048 Q + 512 K + 512 V)
#define SCALEc 0.08838834764831845f  // D^-0.5
#define N_ITEMS 1024                 // 32 qtiles * 16 heads * 2 batch

typedef _Float16 f16;
typedef _Float16 f16x2 __attribute__((ext_vector_type(2)));
typedef _Float16 f16x4 __attribute__((ext_vector_type(4)));
typedef _Float16 f16x8 __attribute__((ext_vector_type(8)));
typedef float    f32x4 __attribute__((ext_vector_type(4)));

// async global->LDS DMA, 16B per lane; LDS dest = (wave-uniform) base + lane*16
__device__ __forceinline__ void gl_lds16(const void* g, void* l) {
  __builtin_amdgcn_global_load_lds(
      (const __attribute__((address_space(1))) unsigned int*)g,
      (__attribute__((address_space(3))) unsigned int*)l, 16, 0, 0);
}

// ---------------------------------------------------------------- convert hs (x4 vec) + ctr init
__global__ __launch_bounds__(256) void conv_hs(const float* __restrict__ in,
                                               f16* __restrict__ out,
                                               int* __restrict__ ctr) {
  if (blockIdx.x == 0 && threadIdx.x == 0) *ctr = 0;
  int i = (blockIdx.x * 256 + threadIdx.x) * 4;
  float4 v = *(const float4*)&in[i];
  f16x4 o; o[0] = (f16)v.x; o[1] = (f16)v.y; o[2] = (f16)v.z; o[3] = (f16)v.w;
  *(f16x4*)&out[i] = o;
}

// ---------------------------------------------------------------- all weight transposes+convert
// z=0: wq->wqkvT[0..2048)   z=1: wk->wqkvT[2048..2560)  z=2: wv->wqkvT[2560..3072)
// z=3: wo->woT[0..2048)     (in: f32 2048 x C; out rows rowOff+c, row stride 2048)
__global__ __launch_bounds__(256) void trw_all(const float* __restrict__ wq,
                                               const float* __restrict__ wk,
                                               const float* __restrict__ wv,
                                               const float* __restrict__ wo,
                                               f16* __restrict__ wqkvT,
                                               f16* __restrict__ woT) {
  const int z = blockIdx.z;
  const float* in; f16* out; int C, rowOff;
  if (z == 0)      { in = wq; out = wqkvT; C = 2048; rowOff = 0; }
  else if (z == 1) { in = wk; out = wqkvT; C = 512;  rowOff = 2048; }
  else if (z == 2) { in = wv; out = wqkvT; C = 512;  rowOff = 2560; }
  else             { in = wo; out = woT;   C = 2048; rowOff = 0; }
  if (blockIdx.x * 64 >= C) return;
  __shared__ float Ld[64 * 65];
  const int tid = threadIdx.x;
  const int r0 = blockIdx.y * 64, c0 = blockIdx.x * 64;
#pragma unroll
  for (int p = 0; p < 4; ++p) {
    int idx = p * 256 + tid;
    int r = idx >> 4, c4 = (idx & 15) * 4;
    float4 v = *(const float4*)&in[(size_t)(r0 + r) * C + c0 + c4];
    Ld[r * 65 + c4 + 0] = v.x; Ld[r * 65 + c4 + 1] = v.y;
    Ld[r * 65 + c4 + 2] = v.z; Ld[r * 65 + c4 + 3] = v.w;
  }
  __syncthreads();
#pragma unroll
  for (int p = 0; p < 4; ++p) {
    int idx = p * 256 + tid;
    int oc = idx >> 4, m4 = (idx & 15) * 4;
    f16x4 o;
#pragma unroll
    for (int i = 0; i < 4; ++i) o[i] = (f16)Ld[(m4 + i) * 65 + oc];
    *(f16x4*)&out[(size_t)(rowOff + c0 + oc) * 2048 + r0 + m4] = o;
  }
}

// ---------------------------------------------------------------- RoPE (Q then K, one kernel)
__global__ __launch_bounds__(256) void rope_all(f16* __restrict__ x,
                                                const float* __restrict__ cb,
                                                const float* __restrict__ sb) {
  int bid = blockIdx.x;
  int colbase, log2h, idx;
  if (bid < 16384) { colbase = 0;    log2h = 4; idx = bid * 256 + threadIdx.x; }
  else             { colbase = 2048; log2h = 2; idx = (bid - 16384) * 256 + threadIdx.x; }
  int d   = idx & 63;
  int h   = (idx >> 6) & ((1 << log2h) - 1);
  int row = idx >> (6 + log2h);
  f16* p = x + (size_t)row * QKVS + colbase + h * 128;
  float x1 = (float)p[d], x2 = (float)p[64 + d];
  float c = cb[(size_t)row * 128 + d], s = sb[(size_t)row * 128 + d];
  p[d]      = (f16)(x1 * c - x2 * s);
  p[64 + d] = (f16)(x2 * c + x1 * s);
}

// ---------------------------------------------------------------- V transpose
// in: V cols of QKV (row stride 3072, colbase 2560). out: Vt[b][kh][d=128][s=2048]
__global__ __launch_bounds__(256) void v_tr(const f16* __restrict__ QKV,
                                            f16* __restrict__ Vt) {
  __shared__ f16 Ld[64 * 78];
  const int tid = threadIdx.x;
  const int s0 = blockIdx.x * 64, d0 = blockIdx.y * 64;
  const int b = blockIdx.z >> 2, kh = blockIdx.z & 3;
#pragma unroll
  for (int p = 0; p < 2; ++p) {
    int idx = p * 256 + tid;
    int sl = idx >> 3, dc8 = (idx & 7) * 8;
    f16x8 v = *(const f16x8*)&QKV[(size_t)(b * Sc + s0 + sl) * QKVS + 2560 + kh * 128 + d0 + dc8];
#pragma unroll
    for (int i = 0; i < 4; ++i) {
      f16x2 w; w[0] = v[2 * i]; w[1] = v[2 * i + 1];
      *(f16x2*)&Ld[sl * 78 + dc8 + 2 * i] = w;
    }
  }
  __syncthreads();
  {
    int dr = (tid >> 3) * 2, sc8 = (tid & 7) * 8;
    f16x8 r0v, r1v;
#pragma unroll
    for (int j = 0; j < 8; ++j) {
      f16x2 w = *(const f16x2*)&Ld[(sc8 + j) * 78 + dr];
      r0v[j] = w[0]; r1v[j] = w[1];
    }
    size_t obase = ((size_t)(b * KHc + kh) * 128 + d0 + dr) * Sc + s0 + sc8;
    *(f16x8*)&Vt[obase]      = r0v;
    *(f16x8*)&Vt[obase + Sc] = r1v;
  }
}

// ---------------------------------------------------------------- GEMM: C = A @ Bt^T
// A (M,K) f16 row-major; Bt (N,K) f16 row-major. 128x128 tile, BK=64,
// fragment-linear LDS + global_load_lds staging (m97 structure).
__global__ __launch_bounds__(256) void gemm_bt(const f16* __restrict__ A,
                                               const f16* __restrict__ Bt,
                                               void* __restrict__ Cout,
                                               int M, int N, int K, int c_f16) {
  __shared__ f16 Al[128 * 64];  // granule (g=m>>4, kq=k>>3, l16=m&15): slot=(g*8+kq)*16+l16
  __shared__ f16 Bl[128 * 64];
  const int tid  = threadIdx.x;
  const int lane = tid & 63, wave = tid >> 6;
  const int quad = lane >> 4, l16 = lane & 15;
  const int wm = (wave >> 1) * 64, wn = (wave & 1) * 64;
  const int m0 = blockIdx.y * 128, n0 = blockIdx.x * 128;
  f32x4 acc[4][4] = {};

  for (int k0 = 0; k0 < K; k0 += 64) {
    __syncthreads();
#pragma unroll
    for (int p = 0; p < 4; ++p) {
      const int g  = wave * 2 + (p >> 1);
      const int kq = (p & 1) * 4 + quad;
      gl_lds16(&A [(size_t)(m0 + g * 16 + l16) * K + k0 + kq * 8], &Al[(wave * 4 + p) * 64 * 8]);
      gl_lds16(&Bt[(size_t)(n0 + g * 16 + l16) * K + k0 + kq * 8], &Bl[(wave * 4 + p) * 64 * 8]);
    }
    __syncthreads();
#pragma unroll
    for (int ks = 0; ks < 2; ++ks) {
      f16x8 af[4], bf[4];
#pragma unroll
      for (int i = 0; i < 4; ++i)
        af[i] = *(const f16x8*)&Al[((((wave >> 1) * 4 + i) * 8 + ks * 4 + quad) * 16 + l16) * 8];
#pragma unroll
      for (int j = 0; j < 4; ++j)
        bf[j] = *(const f16x8*)&Bl[((((wave & 1) * 4 + j) * 8 + ks * 4 + quad) * 16 + l16) * 8];
#pragma unroll
      for (int i = 0; i < 4; ++i)
#pragma unroll
        for (int j = 0; j < 4; ++j)
          acc[i][j] = __builtin_amdgcn_mfma_f32_16x16x32_f16(af[i], bf[j], acc[i][j], 0, 0, 0);
    }
  }

  if (c_f16) {
    f16* C = (f16*)Cout;
#pragma unroll
    for (int i = 0; i < 4; ++i)
#pragma unroll
      for (int j = 0; j < 4; ++j)
#pragma unroll
        for (int r = 0; r < 4; ++r)
          C[(size_t)(m0 + wm + i * 16 + quad * 4 + r) * N + n0 + wn + j * 16 + l16] =
              (f16)acc[i][j][r];
  } else {
    float* C = (float*)Cout;
#pragma unroll
    for (int i = 0; i < 4; ++i)
#pragma unroll
      for (int j = 0; j < 4; ++j)
#pragma unroll
        for (int r = 0; r < 4; ++r)
          C[(size_t)(m0 + wm + i * 16 + quad * 4 + r) * N + n0 + wn + j * 16 + l16] =
              acc[i][j][r];
  }
}

// ---------------------------------------------------------------- fused causal attention v3
// Persistent blocks (4/CU) + atomic queue; single softmax pass per 64-col ktile;
// per-wave (barrier-free) P transpose reused across the two PV chunks.
__global__ __launch_bounds__(256, 4) void attn_v3(const f16* __restrict__ QKV,
                                                  const f16* __restrict__ Vt,
                                                  f16* __restrict__ Ob,
                                                  int* __restrict__ ctr) {
  __shared__ f16 Kl[64 * 128];   // granule (((kc*2+half)*4+c)*4+quad)*16+l16
  __shared__ f16 Vl[64 * 128];   // granule ((dt*2+kc)*4+quad)*16+l16
  __shared__ f16 Ps[4 * 512];    // per-wave 16x32 P tile: w*512+(col>>3)*128+row*8+(col&7)
  __shared__ int item_s;
  const int tid  = threadIdx.x;
  const int lane = tid & 63, wave = tid >> 6;
  const int quad = lane >> 4, l16 = lane & 15;

  for (;;) {
    if (tid == 0) item_s = atomicAdd(ctr, 1);
    __syncthreads();
    const int item = item_s;
    if (item >= N_ITEMS) break;
    const int qt = 31 - (item >> 5);   // longest first
    const int bh = item & 31;
    const int b = bh >> 4, h = bh & 15, kh = h >> 2;
    const int qbase = qt * 64 + wave * 16;

    f16x8 qf[4];
    {
      const f16* qp = QKV + (size_t)(b * Sc + qbase + l16) * QKVS + h * 128 + quad * 8;
#pragma unroll
      for (int c = 0; c < 4; ++c) qf[c] = *(const f16x8*)(qp + c * 32);
    }
    float m_i[4] = {-1e30f, -1e30f, -1e30f, -1e30f};
    float l_i[4] = {0.f, 0.f, 0.f, 0.f};
    f32x4 o[8] = {};

    const int ktiles = qt + 1;
    for (int kt = 0; kt < ktiles; ++kt) {
      __syncthreads();  // prior iteration's LDS reads done
#pragma unroll
      for (int p = 0; p < 4; ++p) {
        gl_lds16(&QKV[(size_t)(b * Sc + kt * 64 + wave * 16 + l16) * QKVS + 2048 + kh * 128 + p * 32 + quad * 8],
                 &Kl[(wave * 4 + p) * 512]);
        const int dt = wave * 2 + (p >> 1), kc = p & 1;
        gl_lds16(&Vt[(size_t)((b * KHc + kh) * 128 + dt * 16 + l16) * Sc + kt * 64 + kc * 32 + quad * 8],
                 &Vl[(wave * 4 + p) * 512]);
      }
      __syncthreads();  // barrier drains vmcnt -> DMA visible

      // ---- scores for all 4 16-col groups
      f32x4 s[4] = {};
#pragma unroll
      for (int kc = 0; kc < 2; ++kc)
#pragma unroll
        for (int c = 0; c < 4; ++c) {
          f16x8 ka = *(const f16x8*)&Kl[(((kc * 2 + 0) * 4 + c) * 4 + quad) * 128 + l16 * 8];
          f16x8 kb = *(const f16x8*)&Kl[(((kc * 2 + 1) * 4 + c) * 4 + quad) * 128 + l16 * 8];
          s[kc * 2 + 0] = __builtin_amdgcn_mfma_f32_16x16x32_f16(qf[c], ka, s[kc * 2 + 0], 0, 0, 0);
          s[kc * 2 + 1] = __builtin_amdgcn_mfma_f32_16x16x32_f16(qf[c], kb, s[kc * 2 + 1], 0, 0, 0);
        }

      // ---- single softmax pass over 64 cols
      const int cb = kt * 64 + l16;
      const int wb = wave * 512 + (l16 & 7);
      const int rhi = l16 >> 3;
      float e2[4], e3[4], alpha[4];
#pragma unroll
      for (int r = 0; r < 4; ++r) {
        int qrow = qbase + quad * 4 + r;
        float v0 = s[0][r] * SCALEc, v1 = s[1][r] * SCALEc;
        float v2 = s[2][r] * SCALEc, v3 = s[3][r] * SCALEc;
        if (cb      > qrow) v0 = -1e30f;
        if (cb + 16 > qrow) v1 = -1e30f;
        if (cb + 32 > qrow) v2 = -1e30f;
        if (cb + 48 > qrow) v3 = -1e30f;
        float mx = fmaxf(fmaxf(v0, v1), fmaxf(v2, v3));
        mx = fmaxf(mx, __shfl_xor(mx, 1));
        mx = fmaxf(mx, __shfl_xor(mx, 2));
        mx = fmaxf(mx, __shfl_xor(mx, 4));
        mx = fmaxf(mx, __shfl_xor(mx, 8));
        float mnew = fmaxf(m_i[r], mx);
        float al = __expf(m_i[r] - mnew);
        v0 = __expf(v0 - mnew); v1 = __expf(v1 - mnew);
        v2 = __expf(v2 - mnew); v3 = __expf(v3 - mnew);
        float rs = (v0 + v1) + (v2 + v3);
        rs += __shfl_xor(rs, 1);
        rs += __shfl_xor(rs, 2);
        rs += __shfl_xor(rs, 4);
        rs += __shfl_xor(rs, 8);
        l_i[r] = l_i[r] * al + rs;
        m_i[r] = mnew;
        alpha[r] = al;
        int rowoff = (quad * 4 + r) * 8;
        Ps[wb + (rhi + 0) * 128 + rowoff] = (f16)v0;  // group 0 -> Ps cols 0..15
        Ps[wb + (rhi + 2) * 128 + rowoff] = (f16)v1;  // group 1 -> Ps cols 16..31
        e2[r] = v2; e3[r] = v3;
      }
#pragma unroll
      for (int dt = 0; dt < 8; ++dt)
#pragma unroll
        for (int r = 0; r < 4; ++r) o[dt][r] *= alpha[r];

      // ---- PV chunk kc=0 (cols 0..31)
      {
        f16x8 pf = *(const f16x8*)&Ps[wave * 512 + quad * 128 + l16 * 8];
#pragma unroll
        for (int dt = 0; dt < 8; ++dt) {
          f16x8 vf = *(const f16x8*)&Vl[((dt * 2 + 0) * 4 + quad) * 128 + l16 * 8];
          o[dt] = __builtin_amdgcn_mfma_f32_16x16x32_f16(pf, vf, o[dt], 0, 0, 0);
        }
      }
      // ---- PV chunk kc=1 (cols 32..63); wave-local DS is in-order -> WAR-safe
#pragma unroll
      for (int r = 0; r < 4; ++r) {
        int rowoff = (quad * 4 + r) * 8;
        Ps[wb + (rhi + 0) * 128 + rowoff] = (f16)e2[r];
        Ps[wb + (rhi + 2) * 128 + rowoff] = (f16)e3[r];
      }
      {
        f16x8 pf = *(const f16x8*)&Ps[wave * 512 + quad * 128 + l16 * 8];
#pragma unroll
        for (int dt = 0; dt < 8; ++dt) {
          f16x8 vf = *(const f16x8*)&Vl[((dt * 2 + 1) * 4 + quad) * 128 + l16 * 8];
          o[dt] = __builtin_amdgcn_mfma_f32_16x16x32_f16(pf, vf, o[dt], 0, 0, 0);
        }
      }
    }

    float inv[4];
#pragma unroll
    for (int r = 0; r < 4; ++r) inv[r] = 1.0f / l_i[r];
#pragma unroll
    for (int dt = 0; dt < 8; ++dt)
#pragma unroll
      for (int r = 0; r < 4; ++r)
        Ob[(size_t)(b * Sc + qbase + quad * 4 + r) * HDc + h * 128 + dt * 16 + l16] =
            (f16)(o[dt][r] * inv[r]);
  }
}

// ---------------------------------------------------------------- launch
extern "C" void kernel_launch(void* const* d_in, const int* in_sizes, int n_in,
                              void* d_out, int out_size, void* d_ws, size_t ws_size,
                              hipStream_t stream) {
  (void)in_sizes; (void)n_in; (void)out_size; (void)ws_size;
  const float* hs   = (const float*)d_in[0];
  const float* cosb = (const float*)d_in[1];
  const float* sinb = (const float*)d_in[2];
  // d_in[3] = attention_mask: pure causal, in-kernel.
  const float* wq = (const float*)d_in[4];
  const float* wk = (const float*)d_in[5];
  const float* wv = (const float*)d_in[6];
  const float* wo = (const float*)d_in[7];
  float* out = (float*)d_out;

  char* ws = (char*)d_ws;
  int*  ctr = (int*)ws;
  size_t off = 256;
  auto alloc = [&](size_t elems) { f16* p = (f16*)(ws + off); off += elems * sizeof(f16); return p; };
  f16* hsF    = alloc((size_t)Bc * Sc * HIDc);     // 16.8 MB (reused as attn output)
  f16* wqkvT  = alloc((size_t)QKVS * HIDc);        // 12.6 MB
  f16* woT    = alloc((size_t)HIDc * HDc);         //  8.4 MB
  f16* QKVf   = alloc((size_t)Bc * Sc * QKVS);     // 25.2 MB
  f16* Vt_g   = alloc((size_t)Bc * KHc * Dc * Sc); //  4.2 MB
  f16* attnF  = hsF;                               // hsF dead after QKV GEMM

  conv_hs<<<8192, 256, 0, stream>>>(hs, hsF, ctr);
  trw_all<<<dim3(32, 32, 4), 256, 0, stream>>>(wq, wk, wv, wo, wqkvT, woT);

  gemm_bt<<<dim3(24, 32), 256, 0, stream>>>(hsF, wqkvT, QKVf, 4096, QKVS, 2048, 1);

  rope_all<<<20480, 256, 0, stream>>>(QKVf, cosb, sinb);
  v_tr<<<dim3(32, 2, 8), 256, 0, stream>>>(QKVf, Vt_g);

  attn_v3<<<1024, 256, 0, stream>>>(QKVf, Vt_g, attnF, ctr);

  gemm_bt<<<dim3(16, 32), 256, 0, stream>>>(attnF, woT, out, 4096, 2048, 2048, 0);
}

// Round 4
// 450.312 us; speedup vs baseline: 2.5220x; 1.0365x over previous
//
#include <hip/hip_runtime.h>
#include <stdint.h>

// Problem constants (LlamaAttention: B=2, S=2048, HID=2048, H=16, KH=4, D=128)
#define Bc   2
#define Sc   2048
#define HIDc 2048
#define Hc   16
#define KHc  4
#define Dc   128
#define HDc  2048   // H*D
#define KHDc 512    // KH*D
#define QKVS 3072   // fused QKV row stride (2048 Q + 512 K + 512 V)
#define SCALE2c 0.12751744657f       // D^-0.5 * log2(e)  (exp2 domain)
#define N_ITEMS 1536                 // 1024 split halves (qt>=16) + 512 shorts

typedef _Float16 f16;
typedef _Float16 f16x2 __attribute__((ext_vector_type(2)));
typedef _Float16 f16x4 __attribute__((ext_vector_type(4)));
typedef _Float16 f16x8 __attribute__((ext_vector_type(8)));
typedef float    f32x4 __attribute__((ext_vector_type(4)));

// async global->LDS DMA, 16B per lane; LDS dest = (wave-uniform) base + lane*16
__device__ __forceinline__ void gl_lds16(const void* g, void* l) {
  __builtin_amdgcn_global_load_lds(
      (const __attribute__((address_space(1))) unsigned int*)g,
      (__attribute__((address_space(3))) unsigned int*)l, 16, 0, 0);
}

// ---------------------------------------------------------------- convert hs (x4 vec) + ctr init
__global__ __launch_bounds__(256) void conv_hs(const float* __restrict__ in,
                                               f16* __restrict__ out,
                                               int* __restrict__ ctr) {
  if (blockIdx.x == 0 && threadIdx.x == 0) *ctr = 0;
  int i = (blockIdx.x * 256 + threadIdx.x) * 4;
  float4 v = *(const float4*)&in[i];
  f16x4 o; o[0] = (f16)v.x; o[1] = (f16)v.y; o[2] = (f16)v.z; o[3] = (f16)v.w;
  *(f16x4*)&out[i] = o;
}

// ---------------------------------------------------------------- all weight transposes+convert
__global__ __launch_bounds__(256) void trw_all(const float* __restrict__ wq,
                                               const float* __restrict__ wk,
                                               const float* __restrict__ wv,
                                               const float* __restrict__ wo,
                                               f16* __restrict__ wqkvT,
                                               f16* __restrict__ woT) {
  const int z = blockIdx.z;
  const float* in; f16* out; int C, rowOff;
  if (z == 0)      { in = wq; out = wqkvT; C = 2048; rowOff = 0; }
  else if (z == 1) { in = wk; out = wqkvT; C = 512;  rowOff = 2048; }
  else if (z == 2) { in = wv; out = wqkvT; C = 512;  rowOff = 2560; }
  else             { in = wo; out = woT;   C = 2048; rowOff = 0; }
  if (blockIdx.x * 64 >= C) return;
  __shared__ float Ld[64 * 65];
  const int tid = threadIdx.x;
  const int r0 = blockIdx.y * 64, c0 = blockIdx.x * 64;
#pragma unroll
  for (int p = 0; p < 4; ++p) {
    int idx = p * 256 + tid;
    int r = idx >> 4, c4 = (idx & 15) * 4;
    float4 v = *(const float4*)&in[(size_t)(r0 + r) * C + c0 + c4];
    Ld[r * 65 + c4 + 0] = v.x; Ld[r * 65 + c4 + 1] = v.y;
    Ld[r * 65 + c4 + 2] = v.z; Ld[r * 65 + c4 + 3] = v.w;
  }
  __syncthreads();
#pragma unroll
  for (int p = 0; p < 4; ++p) {
    int idx = p * 256 + tid;
    int oc = idx >> 4, m4 = (idx & 15) * 4;
    f16x4 o;
#pragma unroll
    for (int i = 0; i < 4; ++i) o[i] = (f16)Ld[(m4 + i) * 65 + oc];
    *(f16x4*)&out[(size_t)(rowOff + c0 + oc) * 2048 + r0 + m4] = o;
  }
}

// ---------------------------------------------------------------- RoPE (Q then K, one kernel)
__global__ __launch_bounds__(256) void rope_all(f16* __restrict__ x,
                                                const float* __restrict__ cb,
                                                const float* __restrict__ sb) {
  int bid = blockIdx.x;
  int colbase, log2h, idx;
  if (bid < 16384) { colbase = 0;    log2h = 4; idx = bid * 256 + threadIdx.x; }
  else             { colbase = 2048; log2h = 2; idx = (bid - 16384) * 256 + threadIdx.x; }
  int d   = idx & 63;
  int h   = (idx >> 6) & ((1 << log2h) - 1);
  int row = idx >> (6 + log2h);
  f16* p = x + (size_t)row * QKVS + colbase + h * 128;
  float x1 = (float)p[d], x2 = (float)p[64 + d];
  float c = cb[(size_t)row * 128 + d], s = sb[(size_t)row * 128 + d];
  p[d]      = (f16)(x1 * c - x2 * s);
  p[64 + d] = (f16)(x2 * c + x1 * s);
}

// ---------------------------------------------------------------- V transpose
__global__ __launch_bounds__(256) void v_tr(const f16* __restrict__ QKV,
                                            f16* __restrict__ Vt) {
  __shared__ f16 Ld[64 * 78];
  const int tid = threadIdx.x;
  const int s0 = blockIdx.x * 64, d0 = blockIdx.y * 64;
  const int b = blockIdx.z >> 2, kh = blockIdx.z & 3;
#pragma unroll
  for (int p = 0; p < 2; ++p) {
    int idx = p * 256 + tid;
    int sl = idx >> 3, dc8 = (idx & 7) * 8;
    f16x8 v = *(const f16x8*)&QKV[(size_t)(b * Sc + s0 + sl) * QKVS + 2560 + kh * 128 + d0 + dc8];
#pragma unroll
    for (int i = 0; i < 4; ++i) {
      f16x2 w; w[0] = v[2 * i]; w[1] = v[2 * i + 1];
      *(f16x2*)&Ld[sl * 78 + dc8 + 2 * i] = w;
    }
  }
  __syncthreads();
  {
    int dr = (tid >> 3) * 2, sc8 = (tid & 7) * 8;
    f16x8 r0v, r1v;
#pragma unroll
    for (int j = 0; j < 8; ++j) {
      f16x2 w = *(const f16x2*)&Ld[(sc8 + j) * 78 + dr];
      r0v[j] = w[0]; r1v[j] = w[1];
    }
    size_t obase = ((size_t)(b * KHc + kh) * 128 + d0 + dr) * Sc + s0 + sc8;
    *(f16x8*)&Vt[obase]      = r0v;
    *(f16x8*)&Vt[obase + Sc] = r1v;
  }
}

// ---------------------------------------------------------------- GEMM: C = A @ Bt^T
__global__ __launch_bounds__(256) void gemm_bt(const f16* __restrict__ A,
                                               const f16* __restrict__ Bt,
                                               void* __restrict__ Cout,
                                               int M, int N, int K, int c_f16) {
  __shared__ f16 Al[128 * 64];
  __shared__ f16 Bl[128 * 64];
  const int tid  = threadIdx.x;
  const int lane = tid & 63, wave = tid >> 6;
  const int quad = lane >> 4, l16 = lane & 15;
  const int wm = (wave >> 1) * 64, wn = (wave & 1) * 64;
  const int m0 = blockIdx.y * 128, n0 = blockIdx.x * 128;
  f32x4 acc[4][4] = {};

  for (int k0 = 0; k0 < K; k0 += 64) {
    __syncthreads();
#pragma unroll
    for (int p = 0; p < 4; ++p) {
      const int g  = wave * 2 + (p >> 1);
      const int kq = (p & 1) * 4 + quad;
      gl_lds16(&A [(size_t)(m0 + g * 16 + l16) * K + k0 + kq * 8], &Al[(wave * 4 + p) * 512]);
      gl_lds16(&Bt[(size_t)(n0 + g * 16 + l16) * K + k0 + kq * 8], &Bl[(wave * 4 + p) * 512]);
    }
    __syncthreads();
#pragma unroll
    for (int ks = 0; ks < 2; ++ks) {
      f16x8 af[4], bf[4];
#pragma unroll
      for (int i = 0; i < 4; ++i)
        af[i] = *(const f16x8*)&Al[((((wave >> 1) * 4 + i) * 8 + ks * 4 + quad) * 16 + l16) * 8];
#pragma unroll
      for (int j = 0; j < 4; ++j)
        bf[j] = *(const f16x8*)&Bl[((((wave & 1) * 4 + j) * 8 + ks * 4 + quad) * 16 + l16) * 8];
#pragma unroll
      for (int i = 0; i < 4; ++i)
#pragma unroll
        for (int j = 0; j < 4; ++j)
          acc[i][j] = __builtin_amdgcn_mfma_f32_16x16x32_f16(af[i], bf[j], acc[i][j], 0, 0, 0);
    }
  }

  if (c_f16) {
    f16* C = (f16*)Cout;
#pragma unroll
    for (int i = 0; i < 4; ++i)
#pragma unroll
      for (int j = 0; j < 4; ++j)
#pragma unroll
        for (int r = 0; r < 4; ++r)
          C[(size_t)(m0 + wm + i * 16 + quad * 4 + r) * N + n0 + wn + j * 16 + l16] =
              (f16)acc[i][j][r];
  } else {
    float* C = (float*)Cout;
#pragma unroll
    for (int i = 0; i < 4; ++i)
#pragma unroll
      for (int j = 0; j < 4; ++j)
#pragma unroll
        for (int r = 0; r < 4; ++r)
          C[(size_t)(m0 + wm + i * 16 + quad * 4 + r) * N + n0 + wn + j * 16 + l16] =
              acc[i][j][r];
  }
}

// ---------------------------------------------------------------- fused causal attention v4
// Split-K work items (qt>=16 tiles split in two K-halves -> 1536 items, cost
// 8.5..16.5 units; cost-descending queue over 1024 blocks). Row-sums via MFMA
// ones-fragment; exp2 domain. Halves write normalized partial O + (m,l) to ws.
__global__ __launch_bounds__(256, 4) void attn_v4(const f16* __restrict__ QKV,
                                                  const f16* __restrict__ Vt,
                                                  f16* __restrict__ Ob,
                                                  f16* __restrict__ Opart,
                                                  float2* __restrict__ ML,
                                                  int* __restrict__ ctr) {
  __shared__ f16 Kl[64 * 128];
  __shared__ f16 Vl[64 * 128];
  __shared__ f16 Ps[4 * 512];    // per-wave 16x32 P tile: w*512+(col>>3)*128+row*8+(col&7)
  __shared__ int item_s;
  const int tid  = threadIdx.x;
  const int lane = tid & 63, wave = tid >> 6;
  const int quad = lane >> 4, l16 = lane & 15;

  // ones B-fragment: col 0 = 1 -> MFMA accumulates P row-sums into C col 0
  f16x8 ones_f;
#pragma unroll
  for (int i = 0; i < 8; ++i) ones_f[i] = (l16 == 0) ? (f16)1.0f : (f16)0.0f;

  for (;;) {
    if (tid == 0) item_s = atomicAdd(ctr, 1);
    __syncthreads();
    const int item = item_s;
    if (item >= N_ITEMS) break;

    // ---- cost-descending item map: bands c=32..17 (halves qt=c-1 x64;
    // shorts qt=c/2-1 x32 when c even), then shorts qt=7..0.
    int qt, bh, k0t, k1t, hf = -1;
    if (item < 1280) {
      int base = 0, c = 32;
#pragma unroll 1
      for (; c >= 17; --c) {
        int sz = (c & 1) ? 64 : 96;
        if (item < base + sz) break;
        base += sz;
      }
      int off = item - base;
      if (off < 64) {
        qt = c - 1; hf = off >> 5; bh = off & 31;
        int nk = qt + 1, hn = nk >> 1;
        k0t = hf ? hn : 0; k1t = hf ? nk : hn;
      } else {
        qt = (c >> 1) - 1; bh = off - 64; k0t = 0; k1t = qt + 1;
      }
    } else {
      int off = item - 1280;
      qt = 7 - (off >> 5); bh = off & 31; k0t = 0; k1t = qt + 1;
    }
    const int b = bh >> 4, h = bh & 15, kh = h >> 2;
    const int qbase = qt * 64 + wave * 16;

    f16x8 qf[4];
    {
      const f16* qp = QKV + (size_t)(b * Sc + qbase + l16) * QKVS + h * 128 + quad * 8;
#pragma unroll
      for (int c = 0; c < 4; ++c) qf[c] = *(const f16x8*)(qp + c * 32);
    }
    float m_i[4] = {-1e30f, -1e30f, -1e30f, -1e30f};
    f32x4 ls = {};
    f32x4 o[8] = {};

    for (int kt = k0t; kt < k1t; ++kt) {
      __syncthreads();  // prior iteration's LDS reads done
#pragma unroll
      for (int p = 0; p < 4; ++p) {
        gl_lds16(&QKV[(size_t)(b * Sc + kt * 64 + wave * 16 + l16) * QKVS + 2048 + kh * 128 + p * 32 + quad * 8],
                 &Kl[(wave * 4 + p) * 512]);
        const int dt = wave * 2 + (p >> 1), kc = p & 1;
        gl_lds16(&Vt[(size_t)((b * KHc + kh) * 128 + dt * 16 + l16) * Sc + kt * 64 + kc * 32 + quad * 8],
                 &Vl[(wave * 4 + p) * 512]);
      }
      __syncthreads();  // barrier drains vmcnt -> DMA visible

      // ---- scores for all 4 16-col groups
      f32x4 s[4] = {};
#pragma unroll
      for (int kc = 0; kc < 2; ++kc)
#pragma unroll
        for (int c = 0; c < 4; ++c) {
          f16x8 ka = *(const f16x8*)&Kl[(((kc * 2 + 0) * 4 + c) * 4 + quad) * 128 + l16 * 8];
          f16x8 kb = *(const f16x8*)&Kl[(((kc * 2 + 1) * 4 + c) * 4 + quad) * 128 + l16 * 8];
          s[kc * 2 + 0] = __builtin_amdgcn_mfma_f32_16x16x32_f16(qf[c], ka, s[kc * 2 + 0], 0, 0, 0);
          s[kc * 2 + 1] = __builtin_amdgcn_mfma_f32_16x16x32_f16(qf[c], kb, s[kc * 2 + 1], 0, 0, 0);
        }

      // ---- single softmax pass (exp2 domain; sums via MFMA later)
      const int cb = kt * 64 + l16;
      const int wb = wave * 512 + (l16 & 7);
      const int rhi = l16 >> 3;
      float e2[4], e3[4], alpha[4];
#pragma unroll
      for (int r = 0; r < 4; ++r) {
        int qrow = qbase + quad * 4 + r;
        float v0 = s[0][r] * SCALE2c, v1 = s[1][r] * SCALE2c;
        float v2 = s[2][r] * SCALE2c, v3 = s[3][r] * SCALE2c;
        if (cb      > qrow) v0 = -1e30f;
        if (cb + 16 > qrow) v1 = -1e30f;
        if (cb + 32 > qrow) v2 = -1e30f;
        if (cb + 48 > qrow) v3 = -1e30f;
        float mx = fmaxf(fmaxf(v0, v1), fmaxf(v2, v3));
        mx = fmaxf(mx, __shfl_xor(mx, 1));
        mx = fmaxf(mx, __shfl_xor(mx, 2));
        mx = fmaxf(mx, __shfl_xor(mx, 4));
        mx = fmaxf(mx, __shfl_xor(mx, 8));
        float mnew = fmaxf(m_i[r], mx);
        alpha[r] = exp2f(m_i[r] - mnew);
        m_i[r] = mnew;
        v0 = exp2f(v0 - mnew); v1 = exp2f(v1 - mnew);
        v2 = exp2f(v2 - mnew); v3 = exp2f(v3 - mnew);
        int rowoff = (quad * 4 + r) * 8;
        Ps[wb + (rhi + 0) * 128 + rowoff] = (f16)v0;
        Ps[wb + (rhi + 2) * 128 + rowoff] = (f16)v1;
        e2[r] = v2; e3[r] = v3;
      }
#pragma unroll
      for (int r = 0; r < 4; ++r) ls[r] *= alpha[r];
#pragma unroll
      for (int dt = 0; dt < 8; ++dt)
#pragma unroll
        for (int r = 0; r < 4; ++r) o[dt][r] *= alpha[r];

      // ---- PV chunk kc=0 (cols 0..31) + row-sum MFMA
      {
        f16x8 pf = *(const f16x8*)&Ps[wave * 512 + quad * 128 + l16 * 8];
        ls = __builtin_amdgcn_mfma_f32_16x16x32_f16(pf, ones_f, ls, 0, 0, 0);
#pragma unroll
        for (int dt = 0; dt < 8; ++dt) {
          f16x8 vf = *(const f16x8*)&Vl[((dt * 2 + 0) * 4 + quad) * 128 + l16 * 8];
          o[dt] = __builtin_amdgcn_mfma_f32_16x16x32_f16(pf, vf, o[dt], 0, 0, 0);
        }
      }
      // ---- PV chunk kc=1 (cols 32..63); wave-local DS in-order -> WAR-safe
#pragma unroll
      for (int r = 0; r < 4; ++r) {
        int rowoff = (quad * 4 + r) * 8;
        Ps[wb + (rhi + 0) * 128 + rowoff] = (f16)e2[r];
        Ps[wb + (rhi + 2) * 128 + rowoff] = (f16)e3[r];
      }
      {
        f16x8 pf = *(const f16x8*)&Ps[wave * 512 + quad * 128 + l16 * 8];
        ls = __builtin_amdgcn_mfma_f32_16x16x32_f16(pf, ones_f, ls, 0, 0, 0);
#pragma unroll
        for (int dt = 0; dt < 8; ++dt) {
          f16x8 vf = *(const f16x8*)&Vl[((dt * 2 + 1) * 4 + quad) * 128 + l16 * 8];
          o[dt] = __builtin_amdgcn_mfma_f32_16x16x32_f16(pf, vf, o[dt], 0, 0, 0);
        }
      }
    }

    // ---- epilogue: l lives in lanes l16==0 (C col 0); broadcast within quad
    float inv[4], lrow[4];
#pragma unroll
    for (int r = 0; r < 4; ++r) {
      lrow[r] = __shfl(ls[r], lane & 48);
      inv[r] = 1.0f / lrow[r];
    }
    if (hf < 0) {
#pragma unroll
      for (int dt = 0; dt < 8; ++dt)
#pragma unroll
        for (int r = 0; r < 4; ++r)
          Ob[(size_t)(b * Sc + qbase + quad * 4 + r) * HDc + h * 128 + dt * 16 + l16] =
              (f16)(o[dt][r] * inv[r]);
    } else {
      const int tile = (qt - 16) * 32 + bh;
      f16* op = Opart + ((size_t)tile * 2 + hf) * (64 * 128);
#pragma unroll
      for (int dt = 0; dt < 8; ++dt)
#pragma unroll
        for (int r = 0; r < 4; ++r)
          op[(wave * 16 + quad * 4 + r) * 128 + dt * 16 + l16] = (f16)(o[dt][r] * inv[r]);
      if (l16 == 0) {
#pragma unroll
        for (int r = 0; r < 4; ++r) {
          float2 ml; ml.x = m_i[r]; ml.y = lrow[r];
          ML[((size_t)tile * 2 + hf) * 64 + wave * 16 + quad * 4 + r] = ml;
        }
      }
    }
  }
}

// ---------------------------------------------------------------- merge split-K halves
// One block per split tile (qt>=16): O = (w1*O1n + w2*O2n), wi = li*2^(mi-m) normalized.
__global__ __launch_bounds__(256) void attn_merge(const f16* __restrict__ Opart,
                                                  const float2* __restrict__ ML,
                                                  f16* __restrict__ Ob) {
  const int tile = blockIdx.x;
  const int qt = 16 + (tile >> 5), bh = tile & 31;
  const int b = bh >> 4, h = bh & 15;
  const int tid = threadIdx.x;
  const int row = tid >> 2, c0 = (tid & 3) * 32;
  float2 ml1 = ML[(size_t)tile * 2 * 64 + row];
  float2 ml2 = ML[((size_t)tile * 2 + 1) * 64 + row];
  float m = fmaxf(ml1.x, ml2.x);
  float w1 = ml1.y * exp2f(ml1.x - m);
  float w2 = ml2.y * exp2f(ml2.x - m);
  float rinv = 1.0f / (w1 + w2);
  float a1 = w1 * rinv, a2 = w2 * rinv;
  const f16* o1 = Opart + (size_t)tile * 2 * (64 * 128) + row * 128 + c0;
  const f16* o2 = o1 + 64 * 128;
  f16* out = Ob + (size_t)(b * Sc + qt * 64 + row) * HDc + h * 128 + c0;
#pragma unroll
  for (int j = 0; j < 4; ++j) {
    f16x8 x1 = *(const f16x8*)(o1 + j * 8);
    f16x8 x2 = *(const f16x8*)(o2 + j * 8);
    f16x8 y;
#pragma unroll
    for (int i = 0; i < 8; ++i) y[i] = (f16)(a1 * (float)x1[i] + a2 * (float)x2[i]);
    *(f16x8*)(out + j * 8) = y;
  }
}

// ---------------------------------------------------------------- launch
extern "C" void kernel_launch(void* const* d_in, const int* in_sizes, int n_in,
                              void* d_out, int out_size, void* d_ws, size_t ws_size,
                              hipStream_t stream) {
  (void)in_sizes; (void)n_in; (void)out_size; (void)ws_size;
  const float* hs   = (const float*)d_in[0];
  const float* cosb = (const float*)d_in[1];
  const float* sinb = (const float*)d_in[2];
  // d_in[3] = attention_mask: pure causal, in-kernel.
  const float* wq = (const float*)d_in[4];
  const float* wk = (const float*)d_in[5];
  const float* wv = (const float*)d_in[6];
  const float* wo = (const float*)d_in[7];
  float* out = (float*)d_out;

  char* ws = (char*)d_ws;
  int*  ctr = (int*)ws;
  size_t off = 256;
  auto alloc = [&](size_t bytes) { char* p = ws + off; off += (bytes + 255) & ~(size_t)255; return p; };
  f16*  hsF   = (f16*)alloc((size_t)Bc * Sc * HIDc * 2);      // 16.8 MB (reused as attn out)
  f16*  woT   = (f16*)alloc((size_t)HIDc * HDc * 2);          //  8.4 MB
  f16*  QKVf  = (f16*)alloc((size_t)Bc * Sc * QKVS * 2);      // 25.2 MB
  f16*  Vt_g  = (f16*)alloc((size_t)Bc * KHc * Dc * Sc * 2);  //  4.2 MB
  f16*  wqkvT = (f16*)alloc((size_t)QKVS * HIDc * 2);         // 12.6 MB (dead after QKV GEMM)
  // Opart aliases wqkvT (16 MB needs 12.6 + 3.4 fresh tail)
  f16*  Opart = wqkvT;
  size_t opart_bytes = (size_t)512 * 2 * 64 * 128 * 2;        // 16.8 MB
  size_t wqkvT_bytes = (size_t)QKVS * HIDc * 2;
  if (opart_bytes > wqkvT_bytes) off += opart_bytes - wqkvT_bytes;
  float2* ML = (float2*)alloc((size_t)512 * 2 * 64 * sizeof(float2));  // 0.5 MB
  f16*  attnF = hsF;  // hsF dead after QKV GEMM

  conv_hs<<<8192, 256, 0, stream>>>(hs, hsF, ctr);
  trw_all<<<dim3(32, 32, 4), 256, 0, stream>>>(wq, wk, wv, wo, wqkvT, woT);

  gemm_bt<<<dim3(24, 32), 256, 0, stream>>>(hsF, wqkvT, QKVf, 4096, QKVS, 2048, 1);

  rope_all<<<20480, 256, 0, stream>>>(QKVf, cosb, sinb);
  v_tr<<<dim3(32, 2, 8), 256, 0, stream>>>(QKVf, Vt_g);

  attn_v4<<<1024, 256, 0, stream>>>(QKVf, Vt_g, attnF, Opart, ML, ctr);
  attn_merge<<<512, 256, 0, stream>>>(Opart, ML, attnF);

  gemm_bt<<<dim3(16, 32), 256, 0, stream>>>(attnF, woT, out, 4096, 2048, 2048, 0);
}